// Round 2
// baseline (72.380 us; speedup 1.0000x reference)
//
#include <hip/hip_runtime.h>
#include <hip/hip_bf16.h>

// Analytical collapse of the reference (see R0):
//   slot levels [0,1,1,1,1,2,2,2,2,3,3,3], anchors [0,0,0,0,0,1,1,1,1,5,5,5];
//   every atom n*12+k valid, each bead writes only its own atoms, nanmean over
//   beads is identity on the single non-NaN entry per atom.
//
//   rel[k]  = node_output[n,3k:3k+3]/(||.||+1e-5) * bond_lengths[type,k]
//   pos[0]  = bead_pos
//   pos[k]  = bead_pos + rel[k]                     (k=1..4)
//   pos[k]  = (bead_pos + rel[1]) + rel[k]          (k=5..8)
//   pos[k]  = ((bead_pos + rel[1]) + rel[5]) + rel[k] (k=9..11)
//   shift   = sum_k w[k]*pos[k] - bead_pos
//   out[n*12+k] = pos[k] - shift
//
// R1: all global traffic staged through LDS with coalesced float4 accesses;
// bond_lengths table (396 floats) cached in LDS. One thread per bead.

#define N_BEADS 1500
#define K_SLOTS 12
#define BLK 256

__global__ __launch_bounds__(BLK) void hier_recon_kernel(
    const float* __restrict__ node_output,   // (N, 36)
    const float* __restrict__ bead_pos,      // (N, 3)
    const float* __restrict__ weights,       // (N, 12)
    const float* __restrict__ bond_lengths,  // (33, 12) = 396 floats
    const int*   __restrict__ bead_types,    // (N,)
    float*       __restrict__ out)           // (N*12, 3)
{
    __shared__ float sh[BLK * 36];    // 36 KB: node_output stage-in, reused for out
    __shared__ float shw[BLK * 12];   // 12 KB: weights
    __shared__ float shp[BLK * 3];    //  3 KB: bead_pos
    __shared__ float sbl[396];        // 1.6 KB: whole bond_lengths table

    const int tid    = threadIdx.x;
    const int base   = blockIdx.x * BLK;                 // first bead of block
    const int nbeads = min(BLK, N_BEADS - base);         // 256 (or 220 last)
    const int nf4    = nbeads * 9;                       // float4s of node_output

    // ---- coalesced stage-in ----
    {
        const float4* g4 = (const float4*)(node_output + (size_t)base * 36);
        float4* s4 = (float4*)sh;
        for (int i = tid; i < nf4; i += BLK) s4[i] = g4[i];

        const float4* gw4 = (const float4*)(weights + (size_t)base * 12);
        float4* sw4 = (float4*)shw;
        for (int i = tid; i < nbeads * 3; i += BLK) sw4[i] = gw4[i];

        const float* gp = bead_pos + (size_t)base * 3;
        for (int i = tid; i < nbeads * 3; i += BLK) shp[i] = gp[i];

        for (int i = tid; i < 396; i += BLK) sbl[i] = bond_lengths[i];
    }
    __syncthreads();

    const bool active = (tid < nbeads);
    float obuf[36];

    if (active) {
        const float* nf = sh + tid * 36;
        const int t = bead_types[base + tid];
        const float* blp = sbl + t * K_SLOTS;
        const float* wp  = shw + tid * K_SLOTS;

        const float px = shp[tid * 3 + 0];
        const float py = shp[tid * 3 + 1];
        const float pz = shp[tid * 3 + 2];

        float rx[K_SLOTS], ry[K_SLOTS], rz[K_SLOTS];
#pragma unroll
        for (int k = 0; k < K_SLOTS; ++k) {
            float x = nf[3 * k + 0];
            float y = nf[3 * k + 1];
            float z = nf[3 * k + 2];
            float s = blp[k] / (sqrtf(x * x + y * y + z * z) + 1e-5f);
            rx[k] = x * s; ry[k] = y * s; rz[k] = z * s;
        }

        float posx[K_SLOTS], posy[K_SLOTS], posz[K_SLOTS];
        posx[0] = px; posy[0] = py; posz[0] = pz;
#pragma unroll
        for (int k = 1; k <= 4; ++k) {
            posx[k] = px + rx[k]; posy[k] = py + ry[k]; posz[k] = pz + rz[k];
        }
#pragma unroll
        for (int k = 5; k <= 8; ++k) {
            posx[k] = px + rx[1] + rx[k];
            posy[k] = py + ry[1] + ry[k];
            posz[k] = pz + rz[1] + rz[k];
        }
#pragma unroll
        for (int k = 9; k <= 11; ++k) {
            posx[k] = px + rx[1] + rx[5] + rx[k];
            posy[k] = py + ry[1] + ry[5] + ry[k];
            posz[k] = pz + rz[1] + rz[5] + rz[k];
        }

        float cmx = 0.f, cmy = 0.f, cmz = 0.f;
#pragma unroll
        for (int k = 0; k < K_SLOTS; ++k) {
            cmx += wp[k] * posx[k];
            cmy += wp[k] * posy[k];
            cmz += wp[k] * posz[k];
        }
        const float sx = cmx - px, sy = cmy - py, sz = cmz - pz;

#pragma unroll
        for (int k = 0; k < K_SLOTS; ++k) {
            obuf[3 * k + 0] = posx[k] - sx;
            obuf[3 * k + 1] = posy[k] - sy;
            obuf[3 * k + 2] = posz[k] - sz;
        }
    }

    __syncthreads();   // done reading sh; reuse it for output staging
    if (active) {
#pragma unroll
        for (int j = 0; j < 36; ++j) sh[tid * 36 + j] = obuf[j];
    }
    __syncthreads();

    // ---- coalesced stage-out ----
    {
        float4* o4 = (float4*)(out + (size_t)base * 36);
        const float4* so4 = (const float4*)sh;
        for (int i = tid; i < nf4; i += BLK) o4[i] = so4[i];
    }
}

extern "C" void kernel_launch(void* const* d_in, const int* in_sizes, int n_in,
                              void* d_out, int out_size, void* d_ws, size_t ws_size,
                              hipStream_t stream) {
    const float* node_output  = (const float*)d_in[0];  // 54000
    const float* bead_pos     = (const float*)d_in[1];  // 4500
    const float* weights      = (const float*)d_in[2];  // 18000
    const float* bond_lengths = (const float*)d_in[3];  // 396
    const int*   bead_types   = (const int*)d_in[4];    // 1500

    const int grid = (N_BEADS + BLK - 1) / BLK;  // 6
    hier_recon_kernel<<<grid, BLK, 0, stream>>>(
        node_output, bead_pos, weights, bond_lengths, bead_types,
        (float*)d_out);
}